// Round 5
// baseline (94.711 us; speedup 1.0000x reference)
//
#include <hip/hip_runtime.h>

#define N_MICS  192
#define OVERLAP 1024
#define WINDOW  524288
#define ROWLEN  (OVERLAP + WINDOW)
#define BLK     256
#define SPT     4

#define RFL_I(x) __builtin_amdgcn_readfirstlane(x)
#define RFL_F(x) __uint_as_float(__builtin_amdgcn_readfirstlane(__float_as_uint(x)))

// ---------------- delay preamble (exact f32 replication of numpy) ---------
__device__ __forceinline__ void compute_delays(
    const float* __restrict__ pos, const float* __restrict__ mic_pos,
    float* s_dist, int* s_off, float* s_df, int tid)
{
    if (tid < N_MICS) {
        float dx = __fsub_rn(pos[0], mic_pos[tid * 3 + 0]);
        float dy = __fsub_rn(pos[1], mic_pos[tid * 3 + 1]);
        float dz = __fsub_rn(pos[2], mic_pos[tid * 3 + 2]);
        float ss = __fadd_rn(__fadd_rn(__fmul_rn(dx, dx), __fmul_rn(dy, dy)),
                             __fmul_rn(dz, dz));
        s_dist[tid] = __fsqrt_rn(ss);
    }
    __syncthreads();
    if (tid < N_MICS) {
        float mx = s_dist[0];
        for (int i = 1; i < N_MICS; ++i) mx = fmaxf(mx, s_dist[i]);
        float dd = __fsub_rn(s_dist[tid], mx);              // <= 0
        float delay = __fmul_rn(
                          __fmul_rn(__fdiv_rn(-dd, 343000.0f), 768000.0f),
                          0.0625f);                         // /16 exact
        int di = (int)delay;                                // trunc, delay >= 0
        s_off[tid] = tid * ROWLEN + OVERLAP - di;
        s_df[tid]  = __fsub_rn(delay, (float)di);
    }
    __syncthreads();
}

// ---- main: wave covers 256 consecutive samples; thread owns lane+64j -----
// All 8 loads per mic are lane-dense 256B spans (scalar base + lane*4 + imm).
__global__ __launch_bounds__(BLK) void tdbf_kernel(
    const float* __restrict__ pos,
    const float* __restrict__ mic_pos,
    const float* __restrict__ buf,
    float* __restrict__ out)
{
    __shared__ float s_dist[N_MICS];
    __shared__ int   s_off[N_MICS];
    __shared__ float s_df[N_MICS];
    const int tid = threadIdx.x;
    compute_delays(pos, mic_pos, s_dist, s_off, s_df, tid);

    const int lane  = tid & 63;
    const int wid   = tid >> 6;
    const int wbase = blockIdx.x * (BLK * SPT) + wid * 256;  // wave's sample base

    float a0 = 0.f, a1 = 0.f, a2 = 0.f, a3 = 0.f;

    #pragma unroll 6
    for (int m = 0; m < N_MICS; ++m) {
        // wave-uniform: fold off+wbase into one SGPR so loads are saddr+lane*4+imm
        const int   qo = RFL_I(s_off[m] + wbase);
        const float f  = RFL_F(s_df[m]);
        const float* q = buf + qo;
        const float v10 = q[lane];            // dense 256B
        const float v11 = q[lane + 64];
        const float v12 = q[lane + 128];
        const float v13 = q[lane + 192];
        const float v20 = q[lane - 1];        // dense 256B, shifted -1 elem
        const float v21 = q[lane + 63];
        const float v22 = q[lane + 127];
        const float v23 = q[lane + 191];
        const float g   = 1.0f - f;
        a0 = fmaf(v10, g, fmaf(v20, f, a0));
        a1 = fmaf(v11, g, fmaf(v21, f, a1));
        a2 = fmaf(v12, g, fmaf(v22, f, a2));
        a3 = fmaf(v13, g, fmaf(v23, f, a3));
    }

    const float inv = 1.0f / (float)N_MICS;
    out[wbase + lane]       = a0 * inv;       // dense 256B stores
    out[wbase + lane + 64]  = a1 * inv;
    out[wbase + lane + 128] = a2 * inv;
    out[wbase + lane + 192] = a3 * inv;
}

extern "C" void kernel_launch(void* const* d_in, const int* in_sizes, int n_in,
                              void* d_out, int out_size, void* d_ws, size_t ws_size,
                              hipStream_t stream) {
    const float* pos     = (const float*)d_in[0];
    const float* mic_pos = (const float*)d_in[1];
    const float* buf     = (const float*)d_in[2];
    float* out           = (float*)d_out;

    dim3 grid(WINDOW / (BLK * SPT));   // 512 blocks
    dim3 block(BLK);
    tdbf_kernel<<<grid, block, 0, stream>>>(pos, mic_pos, buf, out);
}

// Round 6
// 77.375 us; speedup vs baseline: 1.2241x; 1.2241x over previous
//
#include <hip/hip_runtime.h>

#define N_MICS  192
#define OVERLAP 1024
#define WINDOW  524288
#define ROWLEN  (OVERLAP + WINDOW)
#define BLK     256
#define SPT     4

#define RFL_I(x) __builtin_amdgcn_readfirstlane(x)
#define RFL_F(x) __uint_as_float(__builtin_amdgcn_readfirstlane(__float_as_uint(x)))

// 4-float vector with 4-byte alignment: lets the backend emit one
// global_load_dwordx4 at a dword-aligned (not 16B-aligned) address.
typedef float f4a4 __attribute__((ext_vector_type(4), aligned(4)));

// ---------------- delay preamble (exact f32 replication of numpy) ---------
__device__ __forceinline__ void compute_delays(
    const float* __restrict__ pos, const float* __restrict__ mic_pos,
    float* s_dist, int* s_off, float* s_df, int tid)
{
    if (tid < N_MICS) {
        float dx = __fsub_rn(pos[0], mic_pos[tid * 3 + 0]);
        float dy = __fsub_rn(pos[1], mic_pos[tid * 3 + 1]);
        float dz = __fsub_rn(pos[2], mic_pos[tid * 3 + 2]);
        float ss = __fadd_rn(__fadd_rn(__fmul_rn(dx, dx), __fmul_rn(dy, dy)),
                             __fmul_rn(dz, dz));
        s_dist[tid] = __fsqrt_rn(ss);
    }
    __syncthreads();
    if (tid < N_MICS) {
        float mx = s_dist[0];
        for (int i = 1; i < N_MICS; ++i) mx = fmaxf(mx, s_dist[i]);
        float dd = __fsub_rn(s_dist[tid], mx);              // <= 0
        float delay = __fmul_rn(
                          __fmul_rn(__fdiv_rn(-dd, 343000.0f), 768000.0f),
                          0.0625f);                         // /16 exact
        int di = (int)delay;                                // trunc, delay >= 0
        s_off[tid] = tid * ROWLEN + OVERLAP - di;
        s_df[tid]  = __fsub_rn(delay, (float)di);
    }
    __syncthreads();
}

// ---- main: R2 structure, loads fused to dwordx4 + dword per mic ----------
__global__ __launch_bounds__(BLK) void tdbf_kernel(
    const float* __restrict__ pos,
    const float* __restrict__ mic_pos,
    const float* __restrict__ buf,
    float* __restrict__ out)
{
    __shared__ float s_dist[N_MICS];
    __shared__ int   s_off[N_MICS];
    __shared__ float s_df[N_MICS];
    const int tid = threadIdx.x;
    compute_delays(pos, mic_pos, s_dist, s_off, s_df, tid);

    const int t4 = (blockIdx.x * BLK + tid) * SPT;
    float a0 = 0.f, a1 = 0.f, a2 = 0.f, a3 = 0.f;

    #pragma unroll 6
    for (int m = 0; m < N_MICS; ++m) {
        const int   off = RFL_I(s_off[m]);
        const float f   = RFL_F(s_df[m]);
        const float* p  = buf + off + t4;
        const float vm1 = p[-1];
        const f4a4  w   = *reinterpret_cast<const f4a4*>(p);  // v0..v3, 1 instr
        const float g   = 1.0f - f;
        a0 = fmaf(w.x, g, fmaf(vm1, f, a0));
        a1 = fmaf(w.y, g, fmaf(w.x, f, a1));
        a2 = fmaf(w.z, g, fmaf(w.y, f, a2));
        a3 = fmaf(w.w, g, fmaf(w.z, f, a3));
    }

    const float inv = 1.0f / (float)N_MICS;
    float4 o; o.x = a0 * inv; o.y = a1 * inv; o.z = a2 * inv; o.w = a3 * inv;
    *reinterpret_cast<float4*>(out + t4) = o;   // t4 % 4 == 0 -> 16B aligned
}

extern "C" void kernel_launch(void* const* d_in, const int* in_sizes, int n_in,
                              void* d_out, int out_size, void* d_ws, size_t ws_size,
                              hipStream_t stream) {
    const float* pos     = (const float*)d_in[0];
    const float* mic_pos = (const float*)d_in[1];
    const float* buf     = (const float*)d_in[2];
    float* out           = (float*)d_out;

    dim3 grid(WINDOW / (BLK * SPT));   // 512 blocks
    dim3 block(BLK);
    tdbf_kernel<<<grid, block, 0, stream>>>(pos, mic_pos, buf, out);
}